// Round 1
// baseline (998.395 us; speedup 1.0000x reference)
//
#include <hip/hip_runtime.h>
#include <cstdint>
#include <cstddef>

// Problem constants
#define B_  8
#define N_  4096   // H*W
#define M_  512    // memory slots
#define D_  512    // feature dim (= C)
#define HW_ 4096

// -------- workspace layout (float offsets) --------
// qf      : 0          [B,N,D]   16,777,216
// score   : 16777216   [B,N,M]   16,777,216  (raw, then softmax-over-m in place)
// qu      : 33554432   [B,M,D]    2,097,152
// inv_nrm : 35651584   [B,N]         32,768
// s_at    : 35684352   [B,N]         32,768  (raw score at argmax = row max)
// colmax  : 35717120   [B,M]          4,096  (max over n of raw score)
// assign  : 35721216   [B,N] int     32,768
// total 35,753,984 floats = 143 MB

// K1: l2-normalize over channel + transpose [B,C,N] -> [B,N,C]
__global__ __launch_bounds__(256) void k_norm_transpose(
    const float* __restrict__ q, float* __restrict__ qf,
    float* __restrict__ inv_nrm) {
  __shared__ float tile[32][513];
  __shared__ float red[8][32];
  __shared__ float sinv[32];
  const int b = blockIdx.y;
  const int n0 = blockIdx.x * 32;
  const int tid = threadIdx.x;
  const int tx = tid & 31, ty = tid >> 5;
  const float* qb = q + (size_t)b * D_ * HW_ + n0;
  float ss = 0.f;
  for (int c = ty; c < D_; c += 8) {
    const float v = qb[(size_t)c * HW_ + tx];
    tile[tx][c] = v;
    ss += v * v;
  }
  red[ty][tx] = ss;
  __syncthreads();
  if (ty == 0) {
    float s = 0.f;
#pragma unroll
    for (int r = 0; r < 8; ++r) s += red[r][tx];
    const float inv = 1.0f / fmaxf(sqrtf(s), 1e-12f);
    sinv[tx] = inv;
    inv_nrm[b * N_ + n0 + tx] = inv;
  }
  __syncthreads();
  float* qfb = qf + ((size_t)b * N_ + n0) * D_;
  for (int i = tid; i < 32 * D_; i += 256) {
    const int nl = i >> 9, c = i & 511;
    qfb[(size_t)nl * D_ + c] = tile[nl][c] * sinv[nl];
  }
}

// K2: score[b][n][m] = sum_d qf[b][n][d] * keys[m][d]   (fp32, NT)
__global__ __launch_bounds__(256) void k_gemm_score(
    const float* __restrict__ qf, const float* __restrict__ keys,
    float* __restrict__ score) {
  const int b = blockIdx.z;
  const int n0 = blockIdx.y * 64;
  const int m0 = blockIdx.x * 64;
  __shared__ float As[16][64];  // [k][n]
  __shared__ float Bs[16][64];  // [k][m]
  const int tid = threadIdx.x;
  const int tx = tid & 15, ty = tid >> 4;
  float acc[4][4] = {};
  const float* Ab = qf + (size_t)b * N_ * D_;
  const int lrow = tid >> 2, lc4 = (tid & 3) << 2;
  for (int d0 = 0; d0 < D_; d0 += 16) {
    const float4 av = *(const float4*)(Ab + (size_t)(n0 + lrow) * D_ + d0 + lc4);
    const float4 bv = *(const float4*)(keys + (size_t)(m0 + lrow) * D_ + d0 + lc4);
    As[lc4 + 0][lrow] = av.x; As[lc4 + 1][lrow] = av.y;
    As[lc4 + 2][lrow] = av.z; As[lc4 + 3][lrow] = av.w;
    Bs[lc4 + 0][lrow] = bv.x; Bs[lc4 + 1][lrow] = bv.y;
    Bs[lc4 + 2][lrow] = bv.z; Bs[lc4 + 3][lrow] = bv.w;
    __syncthreads();
#pragma unroll
    for (int k = 0; k < 16; ++k) {
      const float4 a = *(const float4*)&As[k][ty << 2];
      const float4 bb = *(const float4*)&Bs[k][tx << 2];
      const float ar[4] = {a.x, a.y, a.z, a.w};
      const float br[4] = {bb.x, bb.y, bb.z, bb.w};
#pragma unroll
      for (int i = 0; i < 4; ++i)
#pragma unroll
        for (int j = 0; j < 4; ++j)
          acc[i][j] = fmaf(ar[i], br[j], acc[i][j]);
    }
    __syncthreads();
  }
  float* Cb = score + ((size_t)b * N_ + n0 + (ty << 2)) * M_ + m0 + (tx << 2);
#pragma unroll
  for (int i = 0; i < 4; ++i) {
    *(float4*)(Cb + (size_t)i * M_) =
        make_float4(acc[i][0], acc[i][1], acc[i][2], acc[i][3]);
  }
}

// K4: colmax[b][m] = max_n score[b][n][m]  (must run before in-place softmax)
__global__ __launch_bounds__(256) void k_colmax(
    const float* __restrict__ score, float* __restrict__ colmax) {
  const int b = blockIdx.y, m0 = blockIdx.x * 32;
  const int tid = threadIdx.x, tx = tid & 31, ty = tid >> 5;
  const float* sb = score + (size_t)b * N_ * M_ + m0 + tx;
  float mx = -1e30f;
  for (int n = ty; n < N_; n += 8) mx = fmaxf(mx, sb[(size_t)n * M_]);
  __shared__ float red[8][33];
  red[ty][tx] = mx;
  __syncthreads();
  if (ty == 0) {
#pragma unroll
    for (int r = 1; r < 8; ++r) mx = fmaxf(mx, red[r][tx]);
    colmax[b * M_ + m0 + tx] = mx;
  }
}

// K3: per (b,n) row: top-2 (tie: lower index), in-place softmax over m,
//     triplet losses, emit s_at(=rowmax) and assign(=argmax)
__global__ __launch_bounds__(256) void k_softmax_top2(
    float* __restrict__ score, const float* __restrict__ qf,
    const float* __restrict__ keys, float* __restrict__ out2,
    float* __restrict__ out3, float* __restrict__ out4,
    float* __restrict__ s_at, int* __restrict__ assign) {
  const int bn = blockIdx.x;
  const int tid = threadIdx.x;
  float* row = score + (size_t)bn * M_;
  const float v0 = row[tid];
  const float v1 = row[tid + 256];
  float t1v, t2v; int t1i, t2i;
  if (v0 >= v1) { t1v = v0; t1i = tid;       t2v = v1; t2i = tid + 256; }
  else          { t1v = v1; t1i = tid + 256; t2v = v0; t2i = tid; }
  __shared__ float sv1[256], sv2[256];
  __shared__ int   si1[256], si2[256];
  sv1[tid] = t1v; si1[tid] = t1i; sv2[tid] = t2v; si2[tid] = t2i;
  __syncthreads();
  for (int s = 128; s > 0; s >>= 1) {
    if (tid < s) {
      const float a1 = sv1[tid];     const int a1i = si1[tid];
      const float a2 = sv2[tid];     const int a2i = si2[tid];
      const float b1 = sv1[tid + s]; const int b1i = si1[tid + s];
      const float b2 = sv2[tid + s]; const int b2i = si2[tid + s];
      if (b1 > a1 || (b1 == a1 && b1i < a1i)) {
        float n2; int n2i;
        if (a1 > b2 || (a1 == b2 && a1i < b2i)) { n2 = a1; n2i = a1i; }
        else                                    { n2 = b2; n2i = b2i; }
        sv1[tid] = b1; si1[tid] = b1i; sv2[tid] = n2; si2[tid] = n2i;
      } else {
        if (b1 > a2 || (b1 == a2 && b1i < a2i)) { sv2[tid] = b1; si2[tid] = b1i; }
      }
    }
    __syncthreads();
  }
  const float rowmax = sv1[0];
  const int i1 = si1[0];
  const int i2 = si2[0];
  __syncthreads();
  // softmax over m, written in place (each thread rewrites only what it read)
  const float e0 = expf(v0 - rowmax), e1 = expf(v1 - rowmax);
  sv1[tid] = e0 + e1;
  __syncthreads();
  for (int s = 128; s > 0; s >>= 1) {
    if (tid < s) sv1[tid] += sv1[tid + s];
    __syncthreads();
  }
  const float invsum = 1.0f / sv1[0];
  row[tid] = e0 * invsum;
  row[tid + 256] = e1 * invsum;
  __syncthreads();
  // losses
  const float* qrow = qf + (size_t)bn * D_;
  const float* pos = keys + (size_t)i1 * D_;
  const float* neg = keys + (size_t)i2 * D_;
  float* lc = out3 + (size_t)bn * D_;
  float dp = 0.f, dn = 0.f;
  for (int c = tid; c < D_; c += 256) {
    const float qv = qrow[c];
    const float dP = qv - pos[c];
    lc[c] = dP * dP;
    const float a = dP + 1e-6f;
    dp += a * a;
    const float bb = (qv - neg[c]) + 1e-6f;
    dn += bb * bb;
  }
  sv1[tid] = dp; sv2[tid] = dn;
  __syncthreads();
  for (int s = 128; s > 0; s >>= 1) {
    if (tid < s) { sv1[tid] += sv1[tid + s]; sv2[tid] += sv2[tid + s]; }
    __syncthreads();
  }
  if (tid == 0) {
    out2[bn] = fmaxf(sqrtf(sv1[0]) - sqrtf(sv2[0]) + 1.0f, 0.0f);
    out4[bn] = (float)i1;
    s_at[bn] = rowmax;
    assign[bn] = i1;
  }
}

// K5: qu[b][m][:] = sum_{n: assign=m} exp(s_at[b,n]-colmax[b,m]) * qf[b][n][:]
//     (colsum cancels: score_query/max_sq == exp(score - colmax))
__global__ __launch_bounds__(256) void k_update_gather(
    const int* __restrict__ assign, const float* __restrict__ s_at,
    const float* __restrict__ colmax, const float* __restrict__ qf,
    float* __restrict__ qu) {
  const int m = blockIdx.x;
  const int b = blockIdx.y;
  __shared__ int list[4096];
  __shared__ int cnt;
  const int tid = threadIdx.x;
  if (tid == 0) cnt = 0;
  __syncthreads();
  const int* ab = assign + b * N_;
  for (int n = tid; n < N_; n += 256) {
    if (ab[n] == m) { const int p = atomicAdd(&cnt, 1); list[p] = n; }
  }
  __syncthreads();
  const float cm = colmax[b * M_ + m];
  const int c0 = tid, c1 = tid + 256;
  float acc0 = 0.f, acc1 = 0.f;
  const int K = cnt;
  for (int i = 0; i < K; ++i) {
    const int n = list[i];
    const float w = expf(s_at[b * N_ + n] - cm);
    const float* qrow = qf + ((size_t)b * N_ + n) * D_;
    acc0 += w * qrow[c0];
    acc1 += w * qrow[c1];
  }
  float* orow = qu + ((size_t)b * M_ + m) * D_;
  orow[c0] = acc0;
  orow[c1] = acc1;
}

// K6: one scan step: mem[m][:] = l2norm(mem[m][:] + qu_b[m][:])
__global__ __launch_bounds__(256) void k_mem_step(
    const float* __restrict__ qu_b, float* __restrict__ mem) {
  const int m = blockIdx.x;
  const int tid = threadIdx.x;
  const size_t base = (size_t)m * D_;
  const float v0 = mem[base + tid] + qu_b[base + tid];
  const float v1 = mem[base + tid + 256] + qu_b[base + tid + 256];
  __shared__ float red[256];
  red[tid] = v0 * v0 + v1 * v1;
  __syncthreads();
  for (int s = 128; s > 0; s >>= 1) {
    if (tid < s) red[tid] += red[tid + s];
    __syncthreads();
  }
  const float inv = 1.0f / fmaxf(sqrtf(red[0]), 1e-12f);
  mem[base + tid] = v0 * inv;
  mem[base + tid + 256] = v1 * inv;
}

// K7a: updated_query[:, :512, :, :] = q * inv_norm  (original layout, elementwise)
__global__ __launch_bounds__(256) void k_out_first(
    const float* __restrict__ q, const float* __restrict__ inv_nrm,
    float* __restrict__ out0) {
  const size_t i4 = (size_t)blockIdx.x * 256 + threadIdx.x;
  const size_t base = i4 * 4;  // flat into q [B,512,4096]
  const int n = (int)(base & 4095);
  const size_t bc = base >> 12;  // b*512 + c
  const size_t b = bc >> 9;
  const float4 v = *(const float4*)(q + base);
  const float4 w = *(const float4*)(inv_nrm + b * N_ + n);
  *(float4*)(out0 + ((bc + b * 512) << 12) + n) =
      make_float4(v.x * w.x, v.y * w.y, v.z * w.z, v.w * w.w);
}

// K7b: out0[b][512+d][n] = sum_m score_mem[b][n][m] * keys[m][d]  (fp32 NN,
//      transposed write through LDS)
__global__ __launch_bounds__(256) void k_gemm_concat(
    const float* __restrict__ sm, const float* __restrict__ keys,
    float* __restrict__ out0) {
  const int b = blockIdx.z;
  const int n0 = blockIdx.y * 64;
  const int d0 = blockIdx.x * 64;
  __shared__ float As[16][64];    // [k][n]
  __shared__ float Bs[16][64];    // [k][d]
  __shared__ float tileC[64][65];
  const int tid = threadIdx.x;
  const int tx = tid & 15, ty = tid >> 4;
  float acc[4][4] = {};
  const float* Ab = sm + (size_t)b * N_ * M_;
  const int arow = tid >> 2, ac4 = (tid & 3) << 2;
  const int brow = tid >> 4, bc4 = (tid & 15) << 2;
  for (int m0 = 0; m0 < M_; m0 += 16) {
    const float4 av = *(const float4*)(Ab + (size_t)(n0 + arow) * M_ + m0 + ac4);
    const float4 bv = *(const float4*)(keys + (size_t)(m0 + brow) * D_ + d0 + bc4);
    As[ac4 + 0][arow] = av.x; As[ac4 + 1][arow] = av.y;
    As[ac4 + 2][arow] = av.z; As[ac4 + 3][arow] = av.w;
    *(float4*)&Bs[brow][bc4] = bv;
    __syncthreads();
#pragma unroll
    for (int k = 0; k < 16; ++k) {
      const float4 a = *(const float4*)&As[k][ty << 2];
      const float4 bb = *(const float4*)&Bs[k][tx << 2];
      const float ar[4] = {a.x, a.y, a.z, a.w};
      const float br[4] = {bb.x, bb.y, bb.z, bb.w};
#pragma unroll
      for (int i = 0; i < 4; ++i)
#pragma unroll
        for (int j = 0; j < 4; ++j)
          acc[i][j] = fmaf(ar[i], br[j], acc[i][j]);
    }
    __syncthreads();
  }
#pragma unroll
  for (int i = 0; i < 4; ++i)
#pragma unroll
    for (int j = 0; j < 4; ++j)
      tileC[(ty << 2) + i][(tx << 2) + j] = acc[i][j];
  __syncthreads();
  float* ob = out0 + ((size_t)b * 1024 + 512 + d0) * (size_t)HW_ + n0;
  for (int t = tid; t < 64 * 64; t += 256) {
    const int dl = t >> 6, nl = t & 63;
    ob[(size_t)dl * HW_ + nl] = tileC[nl][dl];
  }
}

extern "C" void kernel_launch(void* const* d_in, const int* in_sizes, int n_in,
                              void* d_out, int out_size, void* d_ws, size_t ws_size,
                              hipStream_t stream) {
  const float* q = (const float*)d_in[0];     // [8,512,64,64]
  const float* keys = (const float*)d_in[1];  // [512,512]
  float* out = (float*)d_out;
  float* ws = (float*)d_ws;

  float* qf      = ws;
  float* score   = ws + 16777216;
  float* qu      = ws + 33554432;
  float* inv_nrm = ws + 35651584;
  float* s_at    = ws + 35684352;
  float* colmax  = ws + 35717120;
  int*   assign  = (int*)(ws + 35721216);

  float* out0 = out;             // updated_query  [8,1024,64,64]
  float* out1 = out + 33554432;  // updated_memory [512,512]
  float* out2 = out + 33816576;  // loss_separate  [8,4096]
  float* out3 = out + 33849344;  // loss_compact   [8,4096,512]
  float* out4 = out + 50626560;  // closest idx    [8,4096]

  k_norm_transpose<<<dim3(N_ / 32, B_), 256, 0, stream>>>(q, qf, inv_nrm);
  k_gemm_score<<<dim3(M_ / 64, N_ / 64, B_), 256, 0, stream>>>(qf, keys, score);
  k_colmax<<<dim3(M_ / 32, B_), 256, 0, stream>>>(score, colmax);
  k_softmax_top2<<<dim3(B_ * N_), 256, 0, stream>>>(score, qf, keys, out2, out3,
                                                    out4, s_at, assign);
  k_update_gather<<<dim3(M_, B_), 256, 0, stream>>>(assign, s_at, colmax, qf, qu);

  hipMemcpyAsync(out1, keys, (size_t)M_ * D_ * sizeof(float),
                 hipMemcpyDeviceToDevice, stream);
  for (int b = 0; b < B_; ++b)
    k_mem_step<<<dim3(M_), 256, 0, stream>>>(qu + (size_t)b * M_ * D_, out1);

  k_out_first<<<dim3((B_ * D_ * HW_ / 4) / 256), 256, 0, stream>>>(q, inv_nrm, out0);
  k_gemm_concat<<<dim3(D_ / 64, N_ / 64, B_), 256, 0, stream>>>(score, keys, out0);
}